// Round 16
// baseline (2072.222 us; speedup 1.0000x reference)
//
#include <hip/hip_runtime.h>
#include <math.h>

#define K_NN 20
#define NEG_SLOPE 0.2f

constexpr int NSEG = 8;    // segments per query -> 8 sorted partial lists -> merge
constexpr int BKT  = 16;   // per-query LDS bucket depth (drained every tile)
constexpr int OCAP = 6144; // per-block global overflow capacity (entries)

// ---------------------------------------------------------------------------
// ascending-arrival insert (layer-1 path; arrival order is ascending idx)
__device__ __forceinline__ void insert_sorted(float (&dl)[K_NN], int (&il)[K_NN],
                                              float d, int idx) {
    if (d < dl[K_NN - 1]) {
        dl[K_NN - 1] = d; il[K_NN - 1] = idx;
#pragma unroll
        for (int p = K_NN - 1; p > 0; --p) {
            if (dl[p] < dl[p - 1]) {
                float td = dl[p]; dl[p] = dl[p - 1]; dl[p - 1] = td;
                int   ti = il[p]; il[p] = il[p - 1]; il[p - 1] = ti;
            }
        }
    }
}

// ---------------------------------------------------------------------------
// sq[i] = sum_c x[i][c]^2   (ascending-c FMA chain; must match dot order)
template<int C>
__global__ __launch_bounds__(256) void sqnorm_kernel(const float* __restrict__ x,
                                                     float* __restrict__ sq, int N) {
    int i = blockIdx.x * 256 + threadIdx.x;
    if (i < N) {
        float s = 0.f;
#pragma unroll
        for (int c = 0; c < C; ++c) { float v = x[i * C + c]; s += v * v; }
        sq[i] = s;
    }
}

// x4[i] = {x,y,z, sq}  (same fp chain as sqnorm<3>)
__global__ __launch_bounds__(256) void pack3_kernel(const float* __restrict__ x,
                                                    float4* __restrict__ x4, int N) {
    int i = blockIdx.x * 256 + threadIdx.x;
    if (i < N) {
        float a = x[i * 3], b = x[i * 3 + 1], c = x[i * 3 + 2];
        float s = a * a; s += b * b; s += c * c;
        x4[i] = make_float4(a, b, c, s);
    }
}

// ---------------------------------------------------------------------------
// Layer-1 tau: exact top-20 over points [0,2048); tau = guarded 20th distance.
__global__ __launch_bounds__(128) void tau3_kernel(const float4* __restrict__ x4,
                                                   float* __restrict__ tau, int N) {
    __shared__ float bufD[16 * 128];
    __shared__ int   bufI[16 * 128];
    const int tid = threadIdx.x;
    const int q   = blockIdx.x * 128 + tid;
    const float4 qv = x4[q];

    float dl[K_NN]; int il[K_NN];
#pragma unroll
    for (int p = 0; p < K_NN; ++p) { dl[p] = __builtin_inff(); il[p] = 0; }
    int cnt = 0;

    for (int j0 = 0; j0 < 2048; j0 += 8) {
#pragma unroll
        for (int u = 0; u < 8; ++u) {
            float4 pv = x4[j0 + u];
            float dot = qv.x * pv.x; dot += qv.y * pv.y; dot += qv.z * pv.z;
            float d = (qv.w - 2.f * dot) + pv.w;
            if (d < dl[K_NN - 1]) { bufD[tid + 128 * cnt] = d; bufI[tid + 128 * cnt] = j0 + u; ++cnt; }
        }
        if (__any(cnt >= 8)) {
            for (int u2 = 0; u2 < cnt; ++u2)
                insert_sorted(dl, il, bufD[tid + 128 * u2], bufI[tid + 128 * u2]);
            cnt = 0;
        }
    }
    for (int u2 = 0; u2 < cnt; ++u2)
        insert_sorted(dl, il, bufD[tid + 128 * u2], bufI[tid + 128 * u2]);

    tau[q] = dl[K_NN - 1] * 1.000002f + 2e-6f * qv.w;
}

// ---------------------------------------------------------------------------
// Layer-1 main kNN: thread = query, 8 segments, warm tau gate (d <= tau).
__global__ __launch_bounds__(256) void knn3w_kernel(const float4* __restrict__ x4,
                                                    const float* __restrict__ tau,
                                                    float* __restrict__ pdist,
                                                    int* __restrict__ pidx, int N) {
    __shared__ float4 tile4[128];
    __shared__ float bufD[16 * 256];
    __shared__ int   bufI[16 * 256];
    const int tid = threadIdx.x;
    const int q   = blockIdx.x * 256 + tid;
    const int seg = blockIdx.y;
    const int segLen = N / NSEG;
    const int j0  = seg * segLen;

    const float4 qv = x4[q];
    const float  tq = tau[q];

    float dl[K_NN]; int il[K_NN];
#pragma unroll
    for (int p = 0; p < K_NN; ++p) { dl[p] = __builtin_inff(); il[p] = 0; }
    int cnt = 0;

    for (int t0 = 0; t0 < segLen; t0 += 128) {
        __syncthreads();
        if (tid < 128) tile4[tid] = x4[j0 + t0 + tid];
        __syncthreads();
        for (int jj = 0; jj < 128; jj += 8) {
#pragma unroll
            for (int u = 0; u < 8; ++u) {
                float4 pv = tile4[jj + u];
                float dot = qv.x * pv.x; dot += qv.y * pv.y; dot += qv.z * pv.z;
                float d = (qv.w - 2.f * dot) + pv.w;
                if (d <= tq && d < dl[K_NN - 1]) {
                    bufD[tid + 256 * cnt] = d;
                    bufI[tid + 256 * cnt] = j0 + t0 + jj + u;
                    ++cnt;
                }
            }
            if (__any(cnt >= 8)) {
                for (int u2 = 0; u2 < cnt; ++u2)
                    insert_sorted(dl, il, bufD[tid + 256 * u2], bufI[tid + 256 * u2]);
                cnt = 0;
            }
        }
    }
    for (int u2 = 0; u2 < cnt; ++u2)
        insert_sorted(dl, il, bufD[tid + 256 * u2], bufI[tid + 256 * u2]);

    const size_t base = ((size_t)q * NSEG + seg) * K_NN;
#pragma unroll
    for (int p = 0; p < K_NN; ++p) { pdist[base + p] = dl[p]; pidx[base + p] = il[p]; }
}

// ---------------------------------------------------------------------------
// C=64 tau from previous layer's neighbor graph: tau_q = max d_new(q, prev_nbr).
__global__ __launch_bounds__(256) void tau64_kernel(const float* __restrict__ feat,
                                                    const float* __restrict__ sq,
                                                    const int* __restrict__ knn,
                                                    float* __restrict__ tau, int N) {
    int q = blockIdx.x * 256 + threadIdx.x;
    if (q >= N) return;
    const float4* qrow = (const float4*)&feat[(size_t)q * 64];
    float4 qf[16];
#pragma unroll
    for (int m = 0; m < 16; ++m) qf[m] = qrow[m];
    const float qsq = sq[q];
    float t = 0.f;
    for (int k = 0; k < K_NN; ++k) {
        int j = knn[(size_t)q * K_NN + k];
        const float4* prow = (const float4*)&feat[(size_t)j * 64];
        float dot = 0.f;
#pragma unroll
        for (int m = 0; m < 16; ++m) {
            float4 pv = prow[m];
            dot += qf[m].x * pv.x; dot += qf[m].y * pv.y;
            dot += qf[m].z * pv.z; dot += qf[m].w * pv.w;
        }
        float d = (qsq - 2.f * dot) + sq[j];
        t = fmaxf(t, d);
    }
    tau[q] = t * 1.000002f + 2e-6f * qsq;
}

// ---------------------------------------------------------------------------
// xT[c][i] = x[i][c]  (C = 64)
__global__ __launch_bounds__(256) void transpose64_kernel(const float* __restrict__ xin,
                                                          float* __restrict__ xT, int N) {
    int i = blockIdx.x * 256 + threadIdx.x;
    int c = blockIdx.y;
    xT[(size_t)c * N + i] = xin[(size_t)i * 64 + c];
}

// ---------------------------------------------------------------------------
// Fused distance-GEMM + bucket-select with LDS-resident top-20 lists.
// Round-9 structure with ONE epilogue change: unconditional per-tile drain
// behind a SINGLE barrier (no ovf conditional, no trailing barrier).
//  - ordering: drain(t) vs pushes(t+1) separated by the next tile's 8 cc
//    barriers; concurrent thr_s reads see old (looser -> safe) or new value.
//  - thr tightens EVERY tile -> fewer pushes/atomics in later tiles.
//  - drain is LDS-only; acc dead at epilogue end -> no new cross-barrier
//    register liveness (the 5x-validated spill law is respected).
__global__ __launch_bounds__(256, 2) void fused64s_kernel(const float* __restrict__ xT,
                                                          const float* __restrict__ sq,
                                                          const float* __restrict__ tau,
                                                          float* __restrict__ pdist,
                                                          int* __restrict__ pidx,
                                                          uint2* __restrict__ ovG, int N) {
    __shared__ float qT[64][132];
    __shared__ float pTc[2][8][140];
    __shared__ float qbufD[BKT][128];
    __shared__ int   qbufI[BKT][128];
    __shared__ float lstD[K_NN][128];
    __shared__ int   lstI[K_NN][128];
    __shared__ int   qn[128];
    __shared__ float thr_s[128];
    __shared__ int   ovn;

    const int tid = threadIdx.x;
    const int q0  = blockIdx.x * 128;
    const int seg = blockIdx.y;
    const int segLen = N / NSEG;          // 2048
    const int j0  = seg * segLen;
    uint2* ovBase = ovG + (size_t)(seg * gridDim.x + blockIdx.x) * OCAP;

    const int qg = tid >> 4, pg = tid & 15;
    const int qcol = qg * 8;
    const int pcol = pg * 8 + 4 * (pg >> 2);   // swizzle s(col)=col+4*(col>>5)

    // ---- stage qT once ----
#pragma unroll
    for (int k = 0; k < 8; ++k) {
        int v = tid + 256 * k; int c = v >> 5; int dd = (v & 31) * 4;
        *(float4*)&qT[c][dd] = *(const float4*)&xT[(size_t)c * N + q0 + dd];
    }
    float qsv[8];
    *(float4*)&qsv[0] = *(const float4*)&sq[q0 + qcol];
    *(float4*)&qsv[4] = *(const float4*)&sq[q0 + qcol + 4];
    float qtau[8];
    *(float4*)&qtau[0] = *(const float4*)&tau[q0 + qcol];
    *(float4*)&qtau[4] = *(const float4*)&tau[q0 + qcol + 4];

    if (tid < 128) {
        qn[tid] = 0; thr_s[tid] = __builtin_inff();
#pragma unroll
        for (int p = 0; p < K_NN; ++p) { lstD[p][tid] = __builtin_inff(); lstI[p][tid] = 0x7fffffff; }
    }
    if (tid == 0) ovn = 0;

    const int stc  = tid >> 5;            // pTc stage row 0..7
    const int std_ = (tid & 31) * 4;      // logical stage col
    const int sts  = std_ + 4 * (std_ >> 5);

    // prologue: stage chunk (t=0, cc=0)
    *(float4*)&pTc[0][stc][sts] = *(const float4*)&xT[(size_t)stc * N + j0 + std_];
    __syncthreads();

    int buf = 0;
    for (int t = 0; t < 16; ++t) {
        const int jb = j0 + t * 128;
        float acc[8][8];
#pragma unroll
        for (int i = 0; i < 8; ++i)
#pragma unroll
            for (int j = 0; j < 8; ++j) acc[i][j] = 0.f;

        for (int cc = 0; cc < 8; ++cc) {
            const bool last = (t == 15) && (cc == 7);
            float4 pnext;
            if (!last) {
                const int ncc = (cc + 1) & 7;
                const int njb = (cc == 7) ? jb + 128 : jb;
                pnext = *(const float4*)&xT[(size_t)(ncc * 8 + stc) * N + njb + std_];
            }
#pragma unroll
            for (int c8 = 0; c8 < 8; ++c8) {
                const int c = cc * 8 + c8;
                float4 qa  = *(const float4*)&qT[c][qcol];
                float4 qb4 = *(const float4*)&qT[c][qcol + 4];
                float4 pa  = *(const float4*)&pTc[buf][c8][pcol];
                float4 pb4 = *(const float4*)&pTc[buf][c8][pcol + 4];
                float qf[8] = {qa.x, qa.y, qa.z, qa.w, qb4.x, qb4.y, qb4.z, qb4.w};
                float pf[8] = {pa.x, pa.y, pa.z, pa.w, pb4.x, pb4.y, pb4.z, pb4.w};
#pragma unroll
                for (int i = 0; i < 8; ++i)
#pragma unroll
                    for (int j = 0; j < 8; ++j) acc[i][j] += qf[i] * pf[j];
            }
            if (!last) *(float4*)&pTc[buf ^ 1][stc][sts] = pnext;
            __syncthreads();
            buf ^= 1;
        }

        // ---- epilogue: gate + bucket-push; overflow -> global side-buffer ----
        float psv[8];
        *(float4*)&psv[0] = *(const float4*)&sq[jb + pg * 8];
        *(float4*)&psv[4] = *(const float4*)&sq[jb + pg * 8 + 4];
        float thr_c[8];
#pragma unroll
        for (int i = 0; i < 8; ++i) thr_c[i] = thr_s[qcol + i];
        const int tbase = t * 128;

#pragma unroll
        for (int i = 0; i < 8; ++i) {
#pragma unroll
            for (int j = 0; j < 8; ++j) {
                float d = (qsv[i] - 2.f * acc[i][j]) + psv[j];
                if (d <= qtau[i] && d < thr_c[i]) {
                    int slot = atomicAdd(&qn[qcol + i], 1);
                    if (slot < BKT) {
                        qbufD[slot][qcol + i] = d;
                        qbufI[slot][qcol + i] = tbase + pg * 8 + j;
                    } else {
                        int os = atomicAdd(&ovn, 1);
                        if (os < OCAP)
                            ovBase[os] = make_uint2(__float_as_uint(d),
                                                    (unsigned)(((qcol + i) << 11) | (tbase + pg * 8 + j)));
                    }
                }
            }
        }
        __syncthreads();                     // pushes visible (single barrier)

        // unconditional drain by tid<128 -- NO trailing barrier (ordering to
        // tile t+1's pushes via its 8 cc barriers; stale thr reads are safe).
        if (tid < 128) {
            int c = qn[tid]; c = (c < BKT) ? c : BKT;
            for (int s = 0; s < c; ++s) {
                float d = qbufD[s][tid]; int idx = j0 + qbufI[s][tid];
                float td = lstD[K_NN - 1][tid]; int ti = lstI[K_NN - 1][tid];
                if (d < td || (d == td && idx < ti)) {
                    lstD[K_NN - 1][tid] = d; lstI[K_NN - 1][tid] = idx;
#pragma unroll
                    for (int p = K_NN - 1; p > 0; --p) {
                        float a = lstD[p][tid], b = lstD[p - 1][tid];
                        int  ai = lstI[p][tid], bi = lstI[p - 1][tid];
                        if (a < b || (a == b && ai < bi)) {
                            lstD[p][tid] = b; lstD[p - 1][tid] = a;
                            lstI[p][tid] = bi; lstI[p - 1][tid] = ai;
                        } else break;
                    }
                }
            }
            qn[tid] = 0;
            thr_s[tid] = lstD[K_NN - 1][tid];
        }
    }

    // ---- final drain: (empty) buckets, then global overflow entries ----
    if (tid < 128) {
        int c = qn[tid]; c = (c < BKT) ? c : BKT;   // 0 after last drain; kept for safety
        int tot = ovn; tot = (tot < OCAP) ? tot : OCAP;
        for (int s = 0; s < c + tot; ++s) {
            float d; int idx;
            if (s < c) { d = qbufD[s][tid]; idx = j0 + qbufI[s][tid]; }
            else {
                uint2 v = ovBase[s - c];
                if ((int)(v.y >> 11) != tid) continue;
                d = __uint_as_float(v.x); idx = j0 + (int)(v.y & 2047u);
            }
            float td = lstD[K_NN - 1][tid]; int ti = lstI[K_NN - 1][tid];
            if (d < td || (d == td && idx < ti)) {
                lstD[K_NN - 1][tid] = d; lstI[K_NN - 1][tid] = idx;
#pragma unroll
                for (int p = K_NN - 1; p > 0; --p) {
                    float a = lstD[p][tid], b = lstD[p - 1][tid];
                    int  ai = lstI[p][tid], bi = lstI[p - 1][tid];
                    if (a < b || (a == b && ai < bi)) {
                        lstD[p][tid] = b; lstD[p - 1][tid] = a;
                        lstI[p][tid] = bi; lstI[p - 1][tid] = ai;
                    } else break;
                }
            }
        }
        const size_t base = ((size_t)(q0 + tid) * NSEG + seg) * K_NN;
#pragma unroll
        for (int p = 0; p < K_NN; ++p) { pdist[base + p] = lstD[p][tid]; pidx[base + p] = lstI[p][tid]; }
    }
}

// ---------------------------------------------------------------------------
// Merge NSEG sorted partial lists -> final top-20 per query.
__global__ __launch_bounds__(256) void knn_merge_kernel(const float* __restrict__ pdist,
                                                        const int* __restrict__ pidx,
                                                        int* __restrict__ knn, int N) {
    int q = blockIdx.x * 256 + threadIdx.x;
    if (q >= N) return;
    float dl[K_NN]; int il[K_NN];
#pragma unroll
    for (int p = 0; p < K_NN; ++p) { dl[p] = __builtin_inff(); il[p] = 0; }

    for (int s = 0; s < NSEG; ++s) {
        const long base = ((long)q * NSEG + s) * K_NN;
        for (int p = 0; p < K_NN; ++p) {
            float d = pdist[base + p];
            if (!(d < dl[K_NN - 1])) break;   // list sorted lex ascending; inf tail exits
            insert_sorted(dl, il, d, pidx[base + p]);
        }
    }
#pragma unroll
    for (int p = 0; p < K_NN; ++p) knn[(long)q * K_NN + p] = il[p];
}

// ---------------------------------------------------------------------------
template<int C, int F>
__global__ __launch_bounds__(256) void proj_kernel(const float* __restrict__ x,
                                                   const float* __restrict__ W,
                                                   const float* __restrict__ b,
                                                   float* __restrict__ A,
                                                   float* __restrict__ U, int N) {
    int gid = blockIdx.x * 256 + threadIdx.x;
    int i = gid / F, f = gid % F;
    if (i >= N) return;
    float a = b[f], u = 0.f;
#pragma unroll
    for (int c = 0; c < C; ++c) {
        float xv = x[i * C + c];
        a += xv * W[c * F + f];
        u += xv * W[(C + c) * F + f];
    }
    A[(long)i * F + f] = a;
    U[(long)i * F + f] = u;
}

template<int F>
__global__ __launch_bounds__(256) void agg_kernel(const float* __restrict__ A,
                                                  const float* __restrict__ U,
                                                  const int* __restrict__ knn,
                                                  float* __restrict__ out, int N) {
    int gid = blockIdx.x * 256 + threadIdx.x;
    int i = gid / F, f = gid % F;
    if (i >= N) return;
    float a = A[(long)i * F + f] - U[(long)i * F + f];
    float m = -__builtin_inff();
#pragma unroll
    for (int k = 0; k < K_NN; ++k) {
        int j = knn[(long)i * K_NN + k];
        float v = a + U[(long)j * F + f];
        v = fmaxf(v, v * NEG_SLOPE);
        m = fmaxf(m, v);
    }
    out[(long)i * F + f] = m;
}

// ---------------------------------------------------------------------------
extern "C" void kernel_launch(void* const* d_in, const int* in_sizes, int n_in,
                              void* d_out, int out_size, void* d_ws, size_t ws_size,
                              hipStream_t stream) {
    const float* x  = (const float*)d_in[0];
    const float* W1 = (const float*)d_in[1];
    const float* b1 = (const float*)d_in[2];
    const float* W2 = (const float*)d_in[3];
    const float* b2 = (const float*)d_in[4];
    const float* W3 = (const float*)d_in[5];
    const float* b3 = (const float*)d_in[6];
    const int N = in_sizes[0] / 3;  // 16384

    float* ws  = (float*)d_ws;
    float* sq  = ws;                                   // N
    float* A   = sq + N;                               // 128N
    float* U   = A + (size_t)N * 128;                  // 128N
    float* h1  = U + (size_t)N * 128;                  // 64N
    float* h2  = h1 + (size_t)N * 64;                  // 64N
    float4* x4 = (float4*)(h2 + (size_t)N * 64);       // 4N
    float* xT  = (float*)(x4 + N);                     // 64N
    float* tau = xT + (size_t)N * 64;                  // N
    float* pd  = tau + N;                              // 160N
    int* pidx  = (int*)(pd + (size_t)N * NSEG * K_NN); // 160N
    int* knn   = pidx + (size_t)N * NSEG * K_NN;       // 20N
    uint2* ovG = (uint2*)(knn + (size_t)N * K_NN);     // (N/128)*NSEG*OCAP*8B ~ 50MB
    float* out = (float*)d_out;

    const int qBlocks = N / 256;

    // ---- Layer 1 (C=3 -> F=64) ----
    pack3_kernel<<<qBlocks, 256, 0, stream>>>(x, x4, N);
    tau3_kernel<<<N / 128, 128, 0, stream>>>(x4, tau, N);
    knn3w_kernel<<<dim3(qBlocks, NSEG), 256, 0, stream>>>(x4, tau, pd, pidx, N);
    knn_merge_kernel<<<qBlocks, 256, 0, stream>>>(pd, pidx, knn, N);
    proj_kernel<3, 64><<<(N * 64) / 256, 256, 0, stream>>>(x, W1, b1, A, U, N);
    agg_kernel<64><<<(N * 64) / 256, 256, 0, stream>>>(A, U, knn, h1, N);

    // ---- Layer 2 (C=64 -> F=64) ----
    sqnorm_kernel<64><<<qBlocks, 256, 0, stream>>>(h1, sq, N);
    transpose64_kernel<<<dim3(qBlocks, 64), 256, 0, stream>>>(h1, xT, N);
    tau64_kernel<<<qBlocks, 256, 0, stream>>>(h1, sq, knn, tau, N);   // L1 graph
    fused64s_kernel<<<dim3(N / 128, NSEG), 256, 0, stream>>>(xT, sq, tau, pd, pidx, ovG, N);
    knn_merge_kernel<<<qBlocks, 256, 0, stream>>>(pd, pidx, knn, N);
    proj_kernel<64, 64><<<(N * 64) / 256, 256, 0, stream>>>(h1, W2, b2, A, U, N);
    agg_kernel<64><<<(N * 64) / 256, 256, 0, stream>>>(A, U, knn, h2, N);

    // ---- Layer 3 (C=64 -> F=128) ----
    sqnorm_kernel<64><<<qBlocks, 256, 0, stream>>>(h2, sq, N);
    transpose64_kernel<<<dim3(qBlocks, 64), 256, 0, stream>>>(h2, xT, N);
    tau64_kernel<<<qBlocks, 256, 0, stream>>>(h2, sq, knn, tau, N);   // L2 graph
    fused64s_kernel<<<dim3(N / 128, NSEG), 256, 0, stream>>>(xT, sq, tau, pd, pidx, ovG, N);
    knn_merge_kernel<<<qBlocks, 256, 0, stream>>>(pd, pidx, knn, N);
    proj_kernel<64, 128><<<(N * 128) / 256, 256, 0, stream>>>(h2, W3, b3, A, U, N);
    agg_kernel<128><<<(N * 128) / 256, 256, 0, stream>>>(A, U, knn, out, N);
}

// Round 17
// 1957.256 us; speedup vs baseline: 1.0587x; 1.0587x over previous
//
#include <hip/hip_runtime.h>
#include <math.h>

#define K_NN 20
#define NEG_SLOPE 0.2f

constexpr int NSEG = 8;    // segments per query -> 8 sorted partial lists -> merge
constexpr int BKT  = 16;   // per-query LDS bucket depth
constexpr int OCAP = 6144; // per-block global overflow capacity (entries)

// ---------------------------------------------------------------------------
// ascending-arrival insert (layer-1 path; arrival order is ascending idx)
__device__ __forceinline__ void insert_sorted(float (&dl)[K_NN], int (&il)[K_NN],
                                              float d, int idx) {
    if (d < dl[K_NN - 1]) {
        dl[K_NN - 1] = d; il[K_NN - 1] = idx;
#pragma unroll
        for (int p = K_NN - 1; p > 0; --p) {
            if (dl[p] < dl[p - 1]) {
                float td = dl[p]; dl[p] = dl[p - 1]; dl[p - 1] = td;
                int   ti = il[p]; il[p] = il[p - 1]; il[p - 1] = ti;
            }
        }
    }
}

// ---------------------------------------------------------------------------
// sq[i] = sum_c x[i][c]^2   (ascending-c FMA chain; must match dot order)
template<int C>
__global__ __launch_bounds__(256) void sqnorm_kernel(const float* __restrict__ x,
                                                     float* __restrict__ sq, int N) {
    int i = blockIdx.x * 256 + threadIdx.x;
    if (i < N) {
        float s = 0.f;
#pragma unroll
        for (int c = 0; c < C; ++c) { float v = x[i * C + c]; s += v * v; }
        sq[i] = s;
    }
}

// x4[i] = {x,y,z, sq}  (same fp chain as sqnorm<3>)
__global__ __launch_bounds__(256) void pack3_kernel(const float* __restrict__ x,
                                                    float4* __restrict__ x4, int N) {
    int i = blockIdx.x * 256 + threadIdx.x;
    if (i < N) {
        float a = x[i * 3], b = x[i * 3 + 1], c = x[i * 3 + 2];
        float s = a * a; s += b * b; s += c * c;
        x4[i] = make_float4(a, b, c, s);
    }
}

// ---------------------------------------------------------------------------
// Layer-1 tau: exact top-20 over points [0,2048); tau = guarded 20th distance.
__global__ __launch_bounds__(128) void tau3_kernel(const float4* __restrict__ x4,
                                                   float* __restrict__ tau, int N) {
    __shared__ float bufD[16 * 128];
    __shared__ int   bufI[16 * 128];
    const int tid = threadIdx.x;
    const int q   = blockIdx.x * 128 + tid;
    const float4 qv = x4[q];

    float dl[K_NN]; int il[K_NN];
#pragma unroll
    for (int p = 0; p < K_NN; ++p) { dl[p] = __builtin_inff(); il[p] = 0; }
    int cnt = 0;

    for (int j0 = 0; j0 < 2048; j0 += 8) {
#pragma unroll
        for (int u = 0; u < 8; ++u) {
            float4 pv = x4[j0 + u];
            float dot = qv.x * pv.x; dot += qv.y * pv.y; dot += qv.z * pv.z;
            float d = (qv.w - 2.f * dot) + pv.w;
            if (d < dl[K_NN - 1]) { bufD[tid + 128 * cnt] = d; bufI[tid + 128 * cnt] = j0 + u; ++cnt; }
        }
        if (__any(cnt >= 8)) {
            for (int u2 = 0; u2 < cnt; ++u2)
                insert_sorted(dl, il, bufD[tid + 128 * u2], bufI[tid + 128 * u2]);
            cnt = 0;
        }
    }
    for (int u2 = 0; u2 < cnt; ++u2)
        insert_sorted(dl, il, bufD[tid + 128 * u2], bufI[tid + 128 * u2]);

    tau[q] = dl[K_NN - 1] * 1.000002f + 2e-6f * qv.w;
}

// ---------------------------------------------------------------------------
// Layer-1 main kNN: thread = query, 8 segments, warm tau gate (d <= tau).
__global__ __launch_bounds__(256) void knn3w_kernel(const float4* __restrict__ x4,
                                                    const float* __restrict__ tau,
                                                    float* __restrict__ pdist,
                                                    int* __restrict__ pidx, int N) {
    __shared__ float4 tile4[128];
    __shared__ float bufD[16 * 256];
    __shared__ int   bufI[16 * 256];
    const int tid = threadIdx.x;
    const int q   = blockIdx.x * 256 + tid;
    const int seg = blockIdx.y;
    const int segLen = N / NSEG;
    const int j0  = seg * segLen;

    const float4 qv = x4[q];
    const float  tq = tau[q];

    float dl[K_NN]; int il[K_NN];
#pragma unroll
    for (int p = 0; p < K_NN; ++p) { dl[p] = __builtin_inff(); il[p] = 0; }
    int cnt = 0;

    for (int t0 = 0; t0 < segLen; t0 += 128) {
        __syncthreads();
        if (tid < 128) tile4[tid] = x4[j0 + t0 + tid];
        __syncthreads();
        for (int jj = 0; jj < 128; jj += 8) {
#pragma unroll
            for (int u = 0; u < 8; ++u) {
                float4 pv = tile4[jj + u];
                float dot = qv.x * pv.x; dot += qv.y * pv.y; dot += qv.z * pv.z;
                float d = (qv.w - 2.f * dot) + pv.w;
                if (d <= tq && d < dl[K_NN - 1]) {
                    bufD[tid + 256 * cnt] = d;
                    bufI[tid + 256 * cnt] = j0 + t0 + jj + u;
                    ++cnt;
                }
            }
            if (__any(cnt >= 8)) {
                for (int u2 = 0; u2 < cnt; ++u2)
                    insert_sorted(dl, il, bufD[tid + 256 * u2], bufI[tid + 256 * u2]);
                cnt = 0;
            }
        }
    }
    for (int u2 = 0; u2 < cnt; ++u2)
        insert_sorted(dl, il, bufD[tid + 256 * u2], bufI[tid + 256 * u2]);

    const size_t base = ((size_t)q * NSEG + seg) * K_NN;
#pragma unroll
    for (int p = 0; p < K_NN; ++p) { pdist[base + p] = dl[p]; pidx[base + p] = il[p]; }
}

// ---------------------------------------------------------------------------
// C=64 tau from previous layer's neighbor graph: tau_q = max d_new(q, prev_nbr).
__global__ __launch_bounds__(256) void tau64_kernel(const float* __restrict__ feat,
                                                    const float* __restrict__ sq,
                                                    const int* __restrict__ knn,
                                                    float* __restrict__ tau, int N) {
    int q = blockIdx.x * 256 + threadIdx.x;
    if (q >= N) return;
    const float4* qrow = (const float4*)&feat[(size_t)q * 64];
    float4 qf[16];
#pragma unroll
    for (int m = 0; m < 16; ++m) qf[m] = qrow[m];
    const float qsq = sq[q];
    float t = 0.f;
    for (int k = 0; k < K_NN; ++k) {
        int j = knn[(size_t)q * K_NN + k];
        const float4* prow = (const float4*)&feat[(size_t)j * 64];
        float dot = 0.f;
#pragma unroll
        for (int m = 0; m < 16; ++m) {
            float4 pv = prow[m];
            dot += qf[m].x * pv.x; dot += qf[m].y * pv.y;
            dot += qf[m].z * pv.z; dot += qf[m].w * pv.w;
        }
        float d = (qsq - 2.f * dot) + sq[j];
        t = fmaxf(t, d);
    }
    tau[q] = t * 1.000002f + 2e-6f * qsq;
}

// ---------------------------------------------------------------------------
// xT[c][i] = x[i][c]  (C = 64)
__global__ __launch_bounds__(256) void transpose64_kernel(const float* __restrict__ xin,
                                                          float* __restrict__ xT, int N) {
    int i = blockIdx.x * 256 + threadIdx.x;
    int c = blockIdx.y;
    xT[(size_t)c * N + i] = xin[(size_t)i * 64 + c];
}

// ---------------------------------------------------------------------------
// Fused distance-GEMM + bucket-select with LDS-resident top-20 lists.
// (round-9 configuration, verbatim: best measured, spill-free; round-16's
// unconditional-drain variant measured +8% -- conditional drain is optimal)
__global__ __launch_bounds__(256, 2) void fused64s_kernel(const float* __restrict__ xT,
                                                          const float* __restrict__ sq,
                                                          const float* __restrict__ tau,
                                                          float* __restrict__ pdist,
                                                          int* __restrict__ pidx,
                                                          uint2* __restrict__ ovG, int N) {
    __shared__ float qT[64][132];
    __shared__ float pTc[2][8][140];
    __shared__ float qbufD[BKT][128];
    __shared__ int   qbufI[BKT][128];
    __shared__ float lstD[K_NN][128];
    __shared__ int   lstI[K_NN][128];
    __shared__ int   qn[128];
    __shared__ float thr_s[128];
    __shared__ int   ovf;
    __shared__ int   ovn;

    const int tid = threadIdx.x;
    const int q0  = blockIdx.x * 128;
    const int seg = blockIdx.y;
    const int segLen = N / NSEG;          // 2048
    const int j0  = seg * segLen;
    uint2* ovBase = ovG + (size_t)(seg * gridDim.x + blockIdx.x) * OCAP;

    const int qg = tid >> 4, pg = tid & 15;
    const int qcol = qg * 8;
    const int pcol = pg * 8 + 4 * (pg >> 2);   // swizzle s(col)=col+4*(col>>5)

    // ---- stage qT once ----
#pragma unroll
    for (int k = 0; k < 8; ++k) {
        int v = tid + 256 * k; int c = v >> 5; int dd = (v & 31) * 4;
        *(float4*)&qT[c][dd] = *(const float4*)&xT[(size_t)c * N + q0 + dd];
    }
    float qsv[8];
    *(float4*)&qsv[0] = *(const float4*)&sq[q0 + qcol];
    *(float4*)&qsv[4] = *(const float4*)&sq[q0 + qcol + 4];
    float qtau[8];
    *(float4*)&qtau[0] = *(const float4*)&tau[q0 + qcol];
    *(float4*)&qtau[4] = *(const float4*)&tau[q0 + qcol + 4];

    if (tid < 128) {
        qn[tid] = 0; thr_s[tid] = __builtin_inff();
#pragma unroll
        for (int p = 0; p < K_NN; ++p) { lstD[p][tid] = __builtin_inff(); lstI[p][tid] = 0x7fffffff; }
    }
    if (tid == 0) { ovf = 0; ovn = 0; }

    const int stc  = tid >> 5;            // pTc stage row 0..7
    const int std_ = (tid & 31) * 4;      // logical stage col
    const int sts  = std_ + 4 * (std_ >> 5);

    // prologue: stage chunk (t=0, cc=0)
    *(float4*)&pTc[0][stc][sts] = *(const float4*)&xT[(size_t)stc * N + j0 + std_];
    __syncthreads();

    int buf = 0;
    for (int t = 0; t < 16; ++t) {
        const int jb = j0 + t * 128;
        float acc[8][8];
#pragma unroll
        for (int i = 0; i < 8; ++i)
#pragma unroll
            for (int j = 0; j < 8; ++j) acc[i][j] = 0.f;

        for (int cc = 0; cc < 8; ++cc) {
            const bool last = (t == 15) && (cc == 7);
            float4 pnext;
            if (!last) {
                const int ncc = (cc + 1) & 7;
                const int njb = (cc == 7) ? jb + 128 : jb;
                pnext = *(const float4*)&xT[(size_t)(ncc * 8 + stc) * N + njb + std_];
            }
#pragma unroll
            for (int c8 = 0; c8 < 8; ++c8) {
                const int c = cc * 8 + c8;
                float4 qa  = *(const float4*)&qT[c][qcol];
                float4 qb4 = *(const float4*)&qT[c][qcol + 4];
                float4 pa  = *(const float4*)&pTc[buf][c8][pcol];
                float4 pb4 = *(const float4*)&pTc[buf][c8][pcol + 4];
                float qf[8] = {qa.x, qa.y, qa.z, qa.w, qb4.x, qb4.y, qb4.z, qb4.w};
                float pf[8] = {pa.x, pa.y, pa.z, pa.w, pb4.x, pb4.y, pb4.z, pb4.w};
#pragma unroll
                for (int i = 0; i < 8; ++i)
#pragma unroll
                    for (int j = 0; j < 8; ++j) acc[i][j] += qf[i] * pf[j];
            }
            if (!last) *(float4*)&pTc[buf ^ 1][stc][sts] = pnext;
            __syncthreads();
            buf ^= 1;
        }

        // ---- epilogue: gate + bucket-push; overflow -> global side-buffer ----
        float psv[8];
        *(float4*)&psv[0] = *(const float4*)&sq[jb + pg * 8];
        *(float4*)&psv[4] = *(const float4*)&sq[jb + pg * 8 + 4];
        float thr_c[8];
#pragma unroll
        for (int i = 0; i < 8; ++i) thr_c[i] = thr_s[qcol + i];
        const int tbase = t * 128;

#pragma unroll
        for (int i = 0; i < 8; ++i) {
#pragma unroll
            for (int j = 0; j < 8; ++j) {
                float d = (qsv[i] - 2.f * acc[i][j]) + psv[j];
                if (d <= qtau[i] && d < thr_c[i]) {
                    int slot = atomicAdd(&qn[qcol + i], 1);
                    if (slot < BKT) {
                        qbufD[slot][qcol + i] = d;
                        qbufI[slot][qcol + i] = tbase + pg * 8 + j;
                    } else {
                        int os = atomicAdd(&ovn, 1);
                        if (os < OCAP)
                            ovBase[os] = make_uint2(__float_as_uint(d),
                                                    (unsigned)(((qcol + i) << 11) | (tbase + pg * 8 + j)));
                        ovf = 1;
                    }
                }
            }
        }
        __syncthreads();                     // pushes visible
        const int doDrain = ovf;             // uniform read
        __syncthreads();                     // all reads complete
        if (doDrain) {
            if (tid < 128) {
                int c = qn[tid]; c = (c < BKT) ? c : BKT;
                for (int s = 0; s < c; ++s) {
                    float d = qbufD[s][tid]; int idx = j0 + qbufI[s][tid];
                    float td = lstD[K_NN - 1][tid]; int ti = lstI[K_NN - 1][tid];
                    if (d < td || (d == td && idx < ti)) {
                        lstD[K_NN - 1][tid] = d; lstI[K_NN - 1][tid] = idx;
#pragma unroll
                        for (int p = K_NN - 1; p > 0; --p) {
                            float a = lstD[p][tid], b = lstD[p - 1][tid];
                            int  ai = lstI[p][tid], bi = lstI[p - 1][tid];
                            if (a < b || (a == b && ai < bi)) {
                                lstD[p][tid] = b; lstD[p - 1][tid] = a;
                                lstI[p][tid] = bi; lstI[p - 1][tid] = ai;
                            } else break;
                        }
                    }
                }
                qn[tid] = 0;
                thr_s[tid] = lstD[K_NN - 1][tid];
            }
            if (tid == 0) ovf = 0;
            __syncthreads();
        }
    }

    // ---- final drain: buckets, then global overflow entries ----
    if (tid < 128) {
        int c = qn[tid]; c = (c < BKT) ? c : BKT;
        int tot = ovn; tot = (tot < OCAP) ? tot : OCAP;
        for (int s = 0; s < c + tot; ++s) {
            float d; int idx;
            if (s < c) { d = qbufD[s][tid]; idx = j0 + qbufI[s][tid]; }
            else {
                uint2 v = ovBase[s - c];
                if ((int)(v.y >> 11) != tid) continue;
                d = __uint_as_float(v.x); idx = j0 + (int)(v.y & 2047u);
            }
            float td = lstD[K_NN - 1][tid]; int ti = lstI[K_NN - 1][tid];
            if (d < td || (d == td && idx < ti)) {
                lstD[K_NN - 1][tid] = d; lstI[K_NN - 1][tid] = idx;
#pragma unroll
                for (int p = K_NN - 1; p > 0; --p) {
                    float a = lstD[p][tid], b = lstD[p - 1][tid];
                    int  ai = lstI[p][tid], bi = lstI[p - 1][tid];
                    if (a < b || (a == b && ai < bi)) {
                        lstD[p][tid] = b; lstD[p - 1][tid] = a;
                        lstI[p][tid] = bi; lstI[p - 1][tid] = ai;
                    } else break;
                }
            }
        }
        const size_t base = ((size_t)(q0 + tid) * NSEG + seg) * K_NN;
#pragma unroll
        for (int p = 0; p < K_NN; ++p) { pdist[base + p] = lstD[p][tid]; pidx[base + p] = lstI[p][tid]; }
    }
}

// ---------------------------------------------------------------------------
// Merge NSEG sorted partial lists -> final top-20 per query.
__global__ __launch_bounds__(256) void knn_merge_kernel(const float* __restrict__ pdist,
                                                        const int* __restrict__ pidx,
                                                        int* __restrict__ knn, int N) {
    int q = blockIdx.x * 256 + threadIdx.x;
    if (q >= N) return;
    float dl[K_NN]; int il[K_NN];
#pragma unroll
    for (int p = 0; p < K_NN; ++p) { dl[p] = __builtin_inff(); il[p] = 0; }

    for (int s = 0; s < NSEG; ++s) {
        const long base = ((long)q * NSEG + s) * K_NN;
        for (int p = 0; p < K_NN; ++p) {
            float d = pdist[base + p];
            if (!(d < dl[K_NN - 1])) break;   // list sorted lex ascending; inf tail exits
            insert_sorted(dl, il, d, pidx[base + p]);
        }
    }
#pragma unroll
    for (int p = 0; p < K_NN; ++p) knn[(long)q * K_NN + p] = il[p];
}

// ---------------------------------------------------------------------------
template<int C, int F>
__global__ __launch_bounds__(256) void proj_kernel(const float* __restrict__ x,
                                                   const float* __restrict__ W,
                                                   const float* __restrict__ b,
                                                   float* __restrict__ A,
                                                   float* __restrict__ U, int N) {
    int gid = blockIdx.x * 256 + threadIdx.x;
    int i = gid / F, f = gid % F;
    if (i >= N) return;
    float a = b[f], u = 0.f;
#pragma unroll
    for (int c = 0; c < C; ++c) {
        float xv = x[i * C + c];
        a += xv * W[c * F + f];
        u += xv * W[(C + c) * F + f];
    }
    A[(long)i * F + f] = a;
    U[(long)i * F + f] = u;
}

template<int F>
__global__ __launch_bounds__(256) void agg_kernel(const float* __restrict__ A,
                                                  const float* __restrict__ U,
                                                  const int* __restrict__ knn,
                                                  float* __restrict__ out, int N) {
    int gid = blockIdx.x * 256 + threadIdx.x;
    int i = gid / F, f = gid % F;
    if (i >= N) return;
    float a = A[(long)i * F + f] - U[(long)i * F + f];
    float m = -__builtin_inff();
#pragma unroll
    for (int k = 0; k < K_NN; ++k) {
        int j = knn[(long)i * K_NN + k];
        float v = a + U[(long)j * F + f];
        v = fmaxf(v, v * NEG_SLOPE);
        m = fmaxf(m, v);
    }
    out[(long)i * F + f] = m;
}

// ---------------------------------------------------------------------------
extern "C" void kernel_launch(void* const* d_in, const int* in_sizes, int n_in,
                              void* d_out, int out_size, void* d_ws, size_t ws_size,
                              hipStream_t stream) {
    const float* x  = (const float*)d_in[0];
    const float* W1 = (const float*)d_in[1];
    const float* b1 = (const float*)d_in[2];
    const float* W2 = (const float*)d_in[3];
    const float* b2 = (const float*)d_in[4];
    const float* W3 = (const float*)d_in[5];
    const float* b3 = (const float*)d_in[6];
    const int N = in_sizes[0] / 3;  // 16384

    float* ws  = (float*)d_ws;
    float* sq  = ws;                                   // N
    float* A   = sq + N;                               // 128N
    float* U   = A + (size_t)N * 128;                  // 128N
    float* h1  = U + (size_t)N * 128;                  // 64N
    float* h2  = h1 + (size_t)N * 64;                  // 64N
    float4* x4 = (float4*)(h2 + (size_t)N * 64);       // 4N
    float* xT  = (float*)(x4 + N);                     // 64N
    float* tau = xT + (size_t)N * 64;                  // N
    float* pd  = tau + N;                              // 160N
    int* pidx  = (int*)(pd + (size_t)N * NSEG * K_NN); // 160N
    int* knn   = pidx + (size_t)N * NSEG * K_NN;       // 20N
    uint2* ovG = (uint2*)(knn + (size_t)N * K_NN);     // (N/128)*NSEG*OCAP*8B ~ 50MB
    float* out = (float*)d_out;

    const int qBlocks = N / 256;

    // ---- Layer 1 (C=3 -> F=64) ----
    pack3_kernel<<<qBlocks, 256, 0, stream>>>(x, x4, N);
    tau3_kernel<<<N / 128, 128, 0, stream>>>(x4, tau, N);
    knn3w_kernel<<<dim3(qBlocks, NSEG), 256, 0, stream>>>(x4, tau, pd, pidx, N);
    knn_merge_kernel<<<qBlocks, 256, 0, stream>>>(pd, pidx, knn, N);
    proj_kernel<3, 64><<<(N * 64) / 256, 256, 0, stream>>>(x, W1, b1, A, U, N);
    agg_kernel<64><<<(N * 64) / 256, 256, 0, stream>>>(A, U, knn, h1, N);

    // ---- Layer 2 (C=64 -> F=64) ----
    sqnorm_kernel<64><<<qBlocks, 256, 0, stream>>>(h1, sq, N);
    transpose64_kernel<<<dim3(qBlocks, 64), 256, 0, stream>>>(h1, xT, N);
    tau64_kernel<<<qBlocks, 256, 0, stream>>>(h1, sq, knn, tau, N);   // L1 graph
    fused64s_kernel<<<dim3(N / 128, NSEG), 256, 0, stream>>>(xT, sq, tau, pd, pidx, ovG, N);
    knn_merge_kernel<<<qBlocks, 256, 0, stream>>>(pd, pidx, knn, N);
    proj_kernel<64, 64><<<(N * 64) / 256, 256, 0, stream>>>(h1, W2, b2, A, U, N);
    agg_kernel<64><<<(N * 64) / 256, 256, 0, stream>>>(A, U, knn, h2, N);

    // ---- Layer 3 (C=64 -> F=128) ----
    sqnorm_kernel<64><<<qBlocks, 256, 0, stream>>>(h2, sq, N);
    transpose64_kernel<<<dim3(qBlocks, 64), 256, 0, stream>>>(h2, xT, N);
    tau64_kernel<<<qBlocks, 256, 0, stream>>>(h2, sq, knn, tau, N);   // L2 graph
    fused64s_kernel<<<dim3(N / 128, NSEG), 256, 0, stream>>>(xT, sq, tau, pd, pidx, ovG, N);
    knn_merge_kernel<<<qBlocks, 256, 0, stream>>>(pd, pidx, knn, N);
    proj_kernel<64, 128><<<(N * 128) / 256, 256, 0, stream>>>(h2, W3, b3, A, U, N);
    agg_kernel<128><<<(N * 128) / 256, 256, 0, stream>>>(A, U, knn, out, N);
}